// Round 16
// baseline (282.082 us; speedup 1.0000x reference)
//
#include <hip/hip_runtime.h>
#include <math.h>

#define N_TOK 16384
#define DIM   768
#define FFD   3072
#define NEXP  8
#define EPSV  1e-6f

typedef __attribute__((ext_vector_type(4))) float f32x4;
typedef __attribute__((ext_vector_type(4))) unsigned short u16x4;
typedef __attribute__((ext_vector_type(8))) unsigned short u16x8;
typedef __attribute__((ext_vector_type(8))) __bf16 bf16x8;

static __device__ __forceinline__ unsigned short f2bf(float f) {
    unsigned int u = __builtin_bit_cast(unsigned int, f);
    u += 0x7fffu + ((u >> 16) & 1u);   // round-to-nearest-even
    return (unsigned short)(u >> 16);
}
static __device__ __forceinline__ bf16x8 as_bf(u16x8 v) {
    return __builtin_bit_cast(bf16x8, v);
}
static __device__ __forceinline__ void gload16(const void* g, void* l) {
    __builtin_amdgcn_global_load_lds(
        (const __attribute__((address_space(1))) unsigned int*)g,
        (__attribute__((address_space(3))) unsigned int*)l, 16, 0, 0);
}

// ---------------------------------------------------------------------------
// Setup kernel: blocks [0,4608) convert wi, [4608,8704) RMSNorm+router
// (coalesced rw). Router now also builds the per-256-token-group expert
// histogram via fire-and-forget global atomics (512 distinct counters, ~32
// increments each -> negligible contention; NOT the R1 8-counter disaster).
// blkhist is zeroed by hipMemsetAsync before this kernel.
// ---------------------------------------------------------------------------
__global__ __launch_bounds__(256) void k_setup(
    const float* __restrict__ wi, unsigned short* __restrict__ wib,
    const float* __restrict__ x, const float* __restrict__ lnw,
    const float* __restrict__ rw,
    float* __restrict__ out_logits, float* __restrict__ out_eidx,
    float* __restrict__ topp, int* __restrict__ eidx,
    unsigned short* __restrict__ xn, int* __restrict__ blkhist)
{
    __shared__ float tile[64][65];
    const int t = threadIdx.x;
    const int b = blockIdx.x;

    if (b < 4608) {
        // conv wi[e][DIM][FFD] f32 -> wib[e][FFD][DIM] bf16
        const int bc = FFD >> 6, br = DIM >> 6;
        const int e = b / (bc * br);
        const int rem = b - e * bc * br;
        const int rt = rem / bc, ct = rem - rt * bc;
        {
            const int r = t >> 2, c4 = (t & 3) << 4;
            const float* src = wi + ((size_t)e * DIM + rt * 64 + r) * FFD + ct * 64 + c4;
#pragma unroll
            for (int q = 0; q < 4; q++) {
                float4 f = ((const float4*)src)[q];
                tile[r][c4 + q * 4 + 0] = f.x;
                tile[r][c4 + q * 4 + 1] = f.y;
                tile[r][c4 + q * 4 + 2] = f.z;
                tile[r][c4 + q * 4 + 3] = f.w;
            }
        }
        __syncthreads();
        {
            const int c = t >> 2, r4 = (t & 3) << 4;
            u16x8 o0, o1;
#pragma unroll
            for (int j = 0; j < 8; j++)  o0[j] = f2bf(tile[r4 + j][c]);
#pragma unroll
            for (int j = 0; j < 8; j++)  o1[j] = f2bf(tile[r4 + 8 + j][c]);
            unsigned short* dst = wib + ((size_t)e * FFD + ct * 64 + c) * DIM + rt * 64 + r4;
            *(u16x8*)dst       = o0;
            *(u16x8*)(dst + 8) = o1;
        }
        return;
    }

    // ---- RMSNorm + router: one wave per token ----
    const int wid = t >> 6, lane = t & 63;
    const int tok = (b - 4608) * 4 + wid;
    const size_t base = (size_t)tok * DIM;
    float* xvs = ((float*)tile) + wid * 768;

    float4 v[3];
#pragma unroll
    for (int j = 0; j < 3; j++)
        v[j] = *(const float4*)(x + base + lane * 4 + j * 256);
    float ss = 0.f;
#pragma unroll
    for (int j = 0; j < 3; j++)
        ss += v[j].x * v[j].x + v[j].y * v[j].y + v[j].z * v[j].z + v[j].w * v[j].w;
#pragma unroll
    for (int s = 32; s > 0; s >>= 1) ss += __shfl_xor(ss, s);
    const float rstd = rsqrtf(ss * (1.0f / DIM) + EPSV);

#pragma unroll
    for (int j = 0; j < 3; j++) {
        float4 lw = *(const float4*)(lnw + lane * 4 + j * 256);
        float xv0 = v[j].x * rstd * lw.x, xv1 = v[j].y * rstd * lw.y;
        float xv2 = v[j].z * rstd * lw.z, xv3 = v[j].w * rstd * lw.w;
        u16x4 pk = { f2bf(xv0), f2bf(xv1), f2bf(xv2), f2bf(xv3) };
        *(u16x4*)(xn + base + lane * 4 + j * 256) = pk;
        float4 xq = { xv0, xv1, xv2, xv3 };
        *(float4*)&xvs[lane * 4 + j * 256] = xq;
    }
    __syncthreads();

    float rp = 0.f;
#pragma unroll 8
    for (int q = 0; q < 96; q++) {
        float xvv = xvs[(lane >> 3) + q * 8];
        float rwv = rw[q * 64 + lane];
        rp = fmaf(xvv, rwv, rp);
    }
    rp += __shfl_xor(rp, 8);
    rp += __shfl_xor(rp, 16);
    rp += __shfl_xor(rp, 32);
    if (lane < 8) out_logits[(size_t)tok * 8 + lane] = rp;

    float mx = rp; int am = lane & 7;
#pragma unroll
    for (int s = 1; s < 8; s <<= 1) {
        float o = __shfl_xor(mx, s);
        int  oa = __shfl_xor(am, s);
        if (o > mx || (o == mx && oa < am)) { mx = o; am = oa; }
    }
    float se = expf(rp - mx);
    se += __shfl_xor(se, 1);
    se += __shfl_xor(se, 2);
    se += __shfl_xor(se, 4);
    if (lane == 0) {
        topp[tok] = 1.0f / se;
        out_eidx[tok] = (float)am;
        eidx[tok] = am;
        atomicAdd(&blkhist[(tok >> 8) * 8 + am], 1);
    }
}

// ---------------------------------------------------------------------------
// Scatter with inline prefix (each block recomputes the 64x8 prefix from
// blkhist locally; block 0 writes cnt).
// ---------------------------------------------------------------------------
__global__ __launch_bounds__(256) void k_scatter(
    const int* __restrict__ eidx, const int* __restrict__ blkhist,
    int* __restrict__ list, int* __restrict__ cnt)
{
    __shared__ int h[64 * 8];
    __shared__ int tot[8];
    __shared__ int bb8[8];
    __shared__ int wcnt[4][8];
    const int t = threadIdx.x, b = blockIdx.x;
    const int lane = t & 63, wid = t >> 6;
    h[t] = blkhist[t];
    h[t + 256] = blkhist[t + 256];
    __syncthreads();
    if (t < 8) {
        int s = 0;
        for (int q = 0; q < 64; q++) s += h[q * 8 + t];
        tot[t] = s;
    }
    __syncthreads();
    if (t < 8) {
        int eb = 0;
        for (int q = 0; q < t; q++) eb += tot[q];
        int sp = 0;
        for (int q = 0; q < b; q++) sp += h[q * 8 + t];
        bb8[t] = eb + sp;
        if (b == 0) cnt[t] = tot[t];
    }
    const int tok = b * 256 + t;
    const int e = eidx[tok];
    int wrank = 0;
#pragma unroll
    for (int q = 0; q < 8; q++) {
        unsigned long long m = __ballot(e == q);
        if (e == q) wrank = __popcll(m & ((1ull << lane) - 1ull));
        if (lane == 0) wcnt[wid][q] = __popcll(m);
    }
    __syncthreads();
    int wbase = 0;
#pragma unroll
    for (int w = 0; w < 4; w++)
        if (w < wid) wbase += wcnt[w][e];
    list[bb8[e] + wbase + wrank] = tok;
}

// ---------------------------------------------------------------------------
// GEMM1 + hidden conv(wo): blocks [0,1632) = proven 128x256 BK=64
// single-buffer 2-barrier grouped-GEMM; blocks [1632,6240) convert
// wo -> wob bf16 transposed, hiding 151MB under gemm1's compute.
// ---------------------------------------------------------------------------
__global__ __launch_bounds__(256, 2) void k_gemm1(
    const unsigned short* __restrict__ A, const unsigned short* __restrict__ Bw,
    const int* __restrict__ list, const int* __restrict__ cnt,
    unsigned short* __restrict__ Hout,
    const float* __restrict__ wo, unsigned short* __restrict__ wob)
{
    constexpr int K   = DIM;
    constexpr int N   = FFD;
    constexpr int TNT = N / 256;                  // 12
    constexpr int NWG = 1632;
    __shared__ unsigned short Asm[128 * 64];      // 16 KB
    __shared__ unsigned short Bsm[256 * 64];      // 32 KB
    __shared__ int tokrow[128];
    __shared__ int spref[9];
    __shared__ int ebase[8];

    const int t = threadIdx.x, lane = t & 63, wid = t >> 6;

    if (blockIdx.x >= NWG) {
        float (*tile)[65] = reinterpret_cast<float(*)[65]>(Bsm);
        const int bb = blockIdx.x - NWG;
        const int bc = DIM >> 6, br = FFD >> 6;
        const int e = bb / (bc * br);
        const int rem = bb - e * bc * br;
        const int rt = rem / bc, ct = rem - rt * bc;
        {
            const int r = t >> 2, c4 = (t & 3) << 4;
            const float* src = wo + ((size_t)e * FFD + rt * 64 + r) * DIM + ct * 64 + c4;
#pragma unroll
            for (int q = 0; q < 4; q++) {
                float4 f = ((const float4*)src)[q];
                tile[r][c4 + q * 4 + 0] = f.x;
                tile[r][c4 + q * 4 + 1] = f.y;
                tile[r][c4 + q * 4 + 2] = f.z;
                tile[r][c4 + q * 4 + 3] = f.w;
            }
        }
        __syncthreads();
        {
            const int c = t >> 2, r4 = (t & 3) << 4;
            u16x8 o0, o1;
#pragma unroll
            for (int j = 0; j < 8; j++)  o0[j] = f2bf(tile[r4 + j][c]);
#pragma unroll
            for (int j = 0; j < 8; j++)  o1[j] = f2bf(tile[r4 + 8 + j][c]);
            unsigned short* dst = wob + ((size_t)e * DIM + ct * 64 + c) * FFD + rt * 64 + r4;
            *(u16x8*)dst       = o0;
            *(u16x8*)(dst + 8) = o1;
        }
        return;
    }

    if (t == 0) {
        int p = 0, qq = 0;
        spref[0] = 0;
#pragma unroll
        for (int e = 0; e < 8; e++) {
            ebase[e] = qq; qq += cnt[e];
            p += (cnt[e] + 127) >> 7;
            spref[e + 1] = p;
        }
    }
    __syncthreads();
    const int total = spref[8] * TNT;
    const int moff = (wid >> 1) * 64, noff = (wid & 1) * 128;
    const int lr = lane & 15, lq = lane >> 4;

    const int xcd = blockIdx.x & 7, rr8 = blockIdx.x >> 3;
    const int bid = xcd * (NWG >> 3) + rr8;

    int arow[4], asub[4], brow[8], bsub[8];
#pragma unroll
    for (int i = 0; i < 4; i++) {
        int c = (wid * 4 + i) * 64 + lane;
        arow[i] = c >> 3;
        asub[i] = (c & 7) ^ (arow[i] & 7);
    }
#pragma unroll
    for (int i = 0; i < 8; i++) {
        int c = (wid * 8 + i) * 64 + lane;
        brow[i] = c >> 3;
        bsub[i] = (c & 7) ^ (brow[i] & 7);
    }

    for (int w = bid; w < total; w += NWG) {
        const int gm = w / TNT, tn = w - gm * TNT;
        int e = 0;
        while (gm >= spref[e + 1]) e++;
        const int ce = cnt[e], eb = ebase[e];
        const int m0 = (gm - spref[e]) * 128, n0 = tn * 256;

        __syncthreads();
        if (t < 128)
            tokrow[t] = (m0 + t < ce) ? list[eb + m0 + t] : list[eb];
        __syncthreads();

        const unsigned short* aP[4];
        const unsigned short* bP[8];
#pragma unroll
        for (int i = 0; i < 4; i++)
            aP[i] = A + (size_t)tokrow[arow[i]] * K + asub[i] * 8;
#pragma unroll
        for (int i = 0; i < 8; i++)
            bP[i] = Bw + ((size_t)e * N + n0 + brow[i]) * K + bsub[i] * 8;

        f32x4 acc[4][8];
#pragma unroll
        for (int mi = 0; mi < 4; mi++)
#pragma unroll
            for (int ni = 0; ni < 8; ni++) acc[mi][ni] = (f32x4){0, 0, 0, 0};

        for (int k0 = 0; k0 < K; k0 += 64) {
#pragma unroll
            for (int i = 0; i < 4; i++)
                gload16(aP[i] + k0, Asm + (wid * 4 + i) * 512);
#pragma unroll
            for (int i = 0; i < 8; i++)
                gload16(bP[i] + k0, Bsm + (wid * 8 + i) * 512);
            __syncthreads();
#pragma unroll
            for (int kf = 0; kf < 2; kf++) {
                const int phys = ((kf * 4 + lq) ^ (lr & 7)) * 8;
                bf16x8 af[4], bfr[8];
#pragma unroll
                for (int mi = 0; mi < 4; mi++)
                    af[mi] = as_bf(*(const u16x8*)&Asm[(moff + mi * 16 + lr) * 64 + phys]);
#pragma unroll
                for (int ni = 0; ni < 8; ni++)
                    bfr[ni] = as_bf(*(const u16x8*)&Bsm[(noff + ni * 16 + lr) * 64 + phys]);
#pragma unroll
                for (int mi = 0; mi < 4; mi++)
#pragma unroll
                    for (int ni = 0; ni < 8; ni++)
                        acc[mi][ni] = __builtin_amdgcn_mfma_f32_16x16x32_bf16(
                            af[mi], bfr[ni], acc[mi][ni], 0, 0, 0);
            }
            __syncthreads();
        }

#pragma unroll
        for (int mi = 0; mi < 4; mi++) {
#pragma unroll
            for (int r4 = 0; r4 < 4; r4++) {
                const int row = moff + mi * 16 + lq * 4 + r4;
                if (m0 + row < ce) {
                    unsigned short* hp = Hout + (size_t)(eb + m0 + row) * FFD + n0 + noff;
#pragma unroll
                    for (int ni = 0; ni < 8; ni++) {
                        float v = acc[mi][ni][r4];
                        v = v > 0.f ? v : 0.f;
                        hp[ni * 16 + lr] = f2bf(v);
                    }
                }
            }
        }
    }
}

// ---------------------------------------------------------------------------
// GEMM2 (proven ~116us): 128x256 tile, BK=64, single-buffer 2-barrier,
// dense A rows from permuted H.
// ---------------------------------------------------------------------------
__global__ __launch_bounds__(256, 2) void k_gemm2(
    const unsigned short* __restrict__ A, const unsigned short* __restrict__ Bw,
    const int* __restrict__ list, const int* __restrict__ cnt,
    const float* __restrict__ hs, const float* __restrict__ topp,
    float* __restrict__ out)
{
    constexpr int K   = FFD;
    constexpr int N   = DIM;
    constexpr int TNT = N / 256;                  // 3
    __shared__ unsigned short Asm[128 * 64];
    __shared__ unsigned short Bsm[256 * 64];
    __shared__ int tokrow[128];
    __shared__ int spref[9];
    __shared__ int ebase[8];

    const int t = threadIdx.x, lane = t & 63, wid = t >> 6;
    if (t == 0) {
        int p = 0, qq = 0;
        spref[0] = 0;
#pragma unroll
        for (int e = 0; e < 8; e++) {
            ebase[e] = qq; qq += cnt[e];
            p += (cnt[e] + 127) >> 7;
            spref[e + 1] = p;
        }
    }
    __syncthreads();
    const int total = spref[8] * TNT;
    const int moff = (wid >> 1) * 64, noff = (wid & 1) * 128;
    const int lr = lane & 15, lq = lane >> 4;

    const int nwg = gridDim.x;
    const int xcd = blockIdx.x & 7, rr8 = blockIdx.x >> 3;
    const int qd = nwg >> 3, rm = nwg & 7;
    const int bid = (xcd < rm ? xcd * (qd + 1) : rm * (qd + 1) + (xcd - rm) * qd) + rr8;

    int arow[4], asub[4], brow[8], bsub[8];
#pragma unroll
    for (int i = 0; i < 4; i++) {
        int c = (wid * 4 + i) * 64 + lane;
        arow[i] = c >> 3;
        asub[i] = (c & 7) ^ (arow[i] & 7);
    }
#pragma unroll
    for (int i = 0; i < 8; i++) {
        int c = (wid * 8 + i) * 64 + lane;
        brow[i] = c >> 3;
        bsub[i] = (c & 7) ^ (brow[i] & 7);
    }

    for (int w = bid; w < total; w += gridDim.x) {
        const int gm = w / TNT, tn = w - gm * TNT;
        int e = 0;
        while (gm >= spref[e + 1]) e++;
        const int ce = cnt[e], eb = ebase[e];
        const int m0 = (gm - spref[e]) * 128, n0 = tn * 256;

        __syncthreads();
        if (t < 128)
            tokrow[t] = (m0 + t < ce) ? list[eb + m0 + t] : list[eb];
        __syncthreads();

        const unsigned short* aP[4];
        const unsigned short* bP[8];
#pragma unroll
        for (int i = 0; i < 4; i++) {
            const int drow = (m0 + arow[i] < ce) ? (m0 + arow[i]) : (ce - 1);
            aP[i] = A + (size_t)(eb + drow) * K + asub[i] * 8;
        }
#pragma unroll
        for (int i = 0; i < 8; i++)
            bP[i] = Bw + ((size_t)e * N + n0 + brow[i]) * K + bsub[i] * 8;

        f32x4 acc[4][8];
#pragma unroll
        for (int mi = 0; mi < 4; mi++)
#pragma unroll
            for (int ni = 0; ni < 8; ni++) acc[mi][ni] = (f32x4){0, 0, 0, 0};

        for (int k0 = 0; k0 < K; k0 += 64) {
#pragma unroll
            for (int i = 0; i < 4; i++)
                gload16(aP[i] + k0, Asm + (wid * 4 + i) * 512);
#pragma unroll
            for (int i = 0; i < 8; i++)
                gload16(bP[i] + k0, Bsm + (wid * 8 + i) * 512);
            __syncthreads();
#pragma unroll
            for (int kf = 0; kf < 2; kf++) {
                const int phys = ((kf * 4 + lq) ^ (lr & 7)) * 8;
                bf16x8 af[4], bfr[8];
#pragma unroll
                for (int mi = 0; mi < 4; mi++)
                    af[mi] = as_bf(*(const u16x8*)&Asm[(moff + mi * 16 + lr) * 64 + phys]);
#pragma unroll
                for (int ni = 0; ni < 8; ni++)
                    bfr[ni] = as_bf(*(const u16x8*)&Bsm[(noff + ni * 16 + lr) * 64 + phys]);
#pragma unroll
                for (int mi = 0; mi < 4; mi++)
#pragma unroll
                    for (int ni = 0; ni < 8; ni++)
                        acc[mi][ni] = __builtin_amdgcn_mfma_f32_16x16x32_bf16(
                            af[mi], bfr[ni], acc[mi][ni], 0, 0, 0);
            }
            __syncthreads();
        }

#pragma unroll
        for (int mi = 0; mi < 4; mi++) {
#pragma unroll
            for (int r4 = 0; r4 < 4; r4++) {
                const int row = moff + mi * 16 + lq * 4 + r4;
                if (m0 + row < ce) {
                    const int tok = tokrow[row];
                    const float tp = topp[tok];
#pragma unroll
                    for (int ni = 0; ni < 8; ni++) {
                        const size_t idx = (size_t)tok * DIM + n0 + noff + ni * 16 + lr;
                        out[idx] = hs[idx] + tp * acc[mi][ni][r4];
                    }
                }
            }
        }
    }
}

// ---------------------------------------------------------------------------
extern "C" void kernel_launch(void* const* d_in, const int* in_sizes, int n_in,
                              void* d_out, int out_size, void* d_ws, size_t ws_size,
                              hipStream_t stream)
{
    const float* hs  = (const float*)d_in[0];
    const float* lnw = (const float*)d_in[1];
    const float* rw  = (const float*)d_in[2];
    const float* wi  = (const float*)d_in[3];
    const float* wo  = (const float*)d_in[4];

    float* out        = (float*)d_out;
    float* out_logits = out + (size_t)N_TOK * DIM;
    float* out_eidx   = out_logits + (size_t)N_TOK * NEXP;

    char* ws = (char*)d_ws;
    size_t off = 0;
    int*   cnt     = (int*)(ws + off);         off += 256;
    int*   list    = (int*)(ws + off);         off += (size_t)N_TOK * 4;
    float* topp    = (float*)(ws + off);       off += (size_t)N_TOK * 4;
    int*   eidx    = (int*)(ws + off);         off += (size_t)N_TOK * 4;
    int*   blkhist = (int*)(ws + off);         off += 4096;
    unsigned short* xn  = (unsigned short*)(ws + off); off += (size_t)N_TOK * DIM * 2;
    unsigned short* Hb  = (unsigned short*)(ws + off); off += (size_t)N_TOK * FFD * 2;
    unsigned short* wob = (unsigned short*)(ws + off);

    // wi^T (bf16 [e][F][D]) lives in d_out's first 37.75 MB: dead before
    // GEMM2's epilogue writes `out` (GEMMs run sequentially).
    unsigned short* wib = (unsigned short*)d_out;

    hipMemsetAsync(blkhist, 0, 64 * 8 * sizeof(int), stream);
    k_setup<<<8704, 256, 0, stream>>>(wi, wib, hs, lnw, rw,
                                      out_logits, out_eidx, topp, eidx, xn,
                                      blkhist);
    k_scatter<<<64, 256, 0, stream>>>(eidx, blkhist, list, cnt);
    k_gemm1<<<6240, 256, 0, stream>>>(xn, wib, list, cnt, Hb, wo, wob);
    k_gemm2<<<408, 256, 0, stream>>>(Hb, wob, list, cnt, hs, topp, out);
}

// Round 17
// 265.171 us; speedup vs baseline: 1.0638x; 1.0638x over previous
//
#include <hip/hip_runtime.h>
#include <math.h>

#define N_TOK 16384
#define DIM   768
#define FFD   3072
#define NEXP  8
#define EPSV  1e-6f

typedef __attribute__((ext_vector_type(4))) float f32x4;
typedef __attribute__((ext_vector_type(4))) unsigned short u16x4;
typedef __attribute__((ext_vector_type(8))) unsigned short u16x8;
typedef __attribute__((ext_vector_type(8))) __bf16 bf16x8;

static __device__ __forceinline__ unsigned short f2bf(float f) {
    unsigned int u = __builtin_bit_cast(unsigned int, f);
    u += 0x7fffu + ((u >> 16) & 1u);   // round-to-nearest-even
    return (unsigned short)(u >> 16);
}
static __device__ __forceinline__ bf16x8 as_bf(u16x8 v) {
    return __builtin_bit_cast(bf16x8, v);
}
static __device__ __forceinline__ void gload16(const void* g, void* l) {
    __builtin_amdgcn_global_load_lds(
        (const __attribute__((address_space(1))) unsigned int*)g,
        (__attribute__((address_space(3))) unsigned int*)l, 16, 0, 0);
}

// ---------------------------------------------------------------------------
// Setup kernel (R15-proven): blocks [0,4608) convert wi, [4608,8704)
// RMSNorm+router (coalesced rw). conv(wo) lives in k_gemm1's grid.
// ---------------------------------------------------------------------------
__global__ __launch_bounds__(256) void k_setup(
    const float* __restrict__ wi, unsigned short* __restrict__ wib,
    const float* __restrict__ x, const float* __restrict__ lnw,
    const float* __restrict__ rw,
    float* __restrict__ out_logits, float* __restrict__ out_eidx,
    float* __restrict__ topp, int* __restrict__ eidx,
    unsigned short* __restrict__ xn)
{
    __shared__ float tile[64][65];
    const int t = threadIdx.x;
    const int b = blockIdx.x;

    if (b < 4608) {
        // conv wi[e][DIM][FFD] f32 -> wib[e][FFD][DIM] bf16
        const int bc = FFD >> 6, br = DIM >> 6;
        const int e = b / (bc * br);
        const int rem = b - e * bc * br;
        const int rt = rem / bc, ct = rem - rt * bc;
        {
            const int r = t >> 2, c4 = (t & 3) << 4;
            const float* src = wi + ((size_t)e * DIM + rt * 64 + r) * FFD + ct * 64 + c4;
#pragma unroll
            for (int q = 0; q < 4; q++) {
                float4 f = ((const float4*)src)[q];
                tile[r][c4 + q * 4 + 0] = f.x;
                tile[r][c4 + q * 4 + 1] = f.y;
                tile[r][c4 + q * 4 + 2] = f.z;
                tile[r][c4 + q * 4 + 3] = f.w;
            }
        }
        __syncthreads();
        {
            const int c = t >> 2, r4 = (t & 3) << 4;
            u16x8 o0, o1;
#pragma unroll
            for (int j = 0; j < 8; j++)  o0[j] = f2bf(tile[r4 + j][c]);
#pragma unroll
            for (int j = 0; j < 8; j++)  o1[j] = f2bf(tile[r4 + 8 + j][c]);
            unsigned short* dst = wib + ((size_t)e * FFD + ct * 64 + c) * DIM + rt * 64 + r4;
            *(u16x8*)dst       = o0;
            *(u16x8*)(dst + 8) = o1;
        }
        return;
    }

    // ---- RMSNorm + router: one wave per token ----
    const int wid = t >> 6, lane = t & 63;
    const int tok = (b - 4608) * 4 + wid;
    const size_t base = (size_t)tok * DIM;
    float* xvs = ((float*)tile) + wid * 768;

    float4 v[3];
#pragma unroll
    for (int j = 0; j < 3; j++)
        v[j] = *(const float4*)(x + base + lane * 4 + j * 256);
    float ss = 0.f;
#pragma unroll
    for (int j = 0; j < 3; j++)
        ss += v[j].x * v[j].x + v[j].y * v[j].y + v[j].z * v[j].z + v[j].w * v[j].w;
#pragma unroll
    for (int s = 32; s > 0; s >>= 1) ss += __shfl_xor(ss, s);
    const float rstd = rsqrtf(ss * (1.0f / DIM) + EPSV);

#pragma unroll
    for (int j = 0; j < 3; j++) {
        float4 lw = *(const float4*)(lnw + lane * 4 + j * 256);
        float xv0 = v[j].x * rstd * lw.x, xv1 = v[j].y * rstd * lw.y;
        float xv2 = v[j].z * rstd * lw.z, xv3 = v[j].w * rstd * lw.w;
        u16x4 pk = { f2bf(xv0), f2bf(xv1), f2bf(xv2), f2bf(xv3) };
        *(u16x4*)(xn + base + lane * 4 + j * 256) = pk;
        float4 xq = { xv0, xv1, xv2, xv3 };
        *(float4*)&xvs[lane * 4 + j * 256] = xq;
    }
    __syncthreads();

    float rp = 0.f;
#pragma unroll 8
    for (int q = 0; q < 96; q++) {
        float xvv = xvs[(lane >> 3) + q * 8];
        float rwv = rw[q * 64 + lane];
        rp = fmaf(xvv, rwv, rp);
    }
    rp += __shfl_xor(rp, 8);
    rp += __shfl_xor(rp, 16);
    rp += __shfl_xor(rp, 32);
    if (lane < 8) out_logits[(size_t)tok * 8 + lane] = rp;

    float mx = rp; int am = lane & 7;
#pragma unroll
    for (int s = 1; s < 8; s <<= 1) {
        float o = __shfl_xor(mx, s);
        int  oa = __shfl_xor(am, s);
        if (o > mx || (o == mx && oa < am)) { mx = o; am = oa; }
    }
    float se = expf(rp - mx);
    se += __shfl_xor(se, 1);
    se += __shfl_xor(se, 2);
    se += __shfl_xor(se, 4);
    if (lane == 0) {
        topp[tok] = 1.0f / se;
        out_eidx[tok] = (float)am;
        eidx[tok] = am;
    }
}

// ---------------------------------------------------------------------------
__global__ __launch_bounds__(256) void k_hist(
    const int* __restrict__ eidx, int* __restrict__ blkhist)
{
    __shared__ int h[8];
    if (threadIdx.x < 8) h[threadIdx.x] = 0;
    __syncthreads();
    atomicAdd(&h[eidx[blockIdx.x * 256 + threadIdx.x]], 1);
    __syncthreads();
    if (threadIdx.x < 8) blkhist[blockIdx.x * 8 + threadIdx.x] = h[threadIdx.x];
}

// ---------------------------------------------------------------------------
// Scatter with inline prefix (each block recomputes the 64x8 prefix locally;
// block 0 writes cnt).
// ---------------------------------------------------------------------------
__global__ __launch_bounds__(256) void k_scatter(
    const int* __restrict__ eidx, const int* __restrict__ blkhist,
    int* __restrict__ list, int* __restrict__ cnt)
{
    __shared__ int h[64 * 8];
    __shared__ int tot[8];
    __shared__ int bb8[8];
    __shared__ int wcnt[4][8];
    const int t = threadIdx.x, b = blockIdx.x;
    const int lane = t & 63, wid = t >> 6;
    h[t] = blkhist[t];
    h[t + 256] = blkhist[t + 256];
    __syncthreads();
    if (t < 8) {
        int s = 0;
        for (int q = 0; q < 64; q++) s += h[q * 8 + t];
        tot[t] = s;
    }
    __syncthreads();
    if (t < 8) {
        int eb = 0;
        for (int q = 0; q < t; q++) eb += tot[q];
        int sp = 0;
        for (int q = 0; q < b; q++) sp += h[q * 8 + t];
        bb8[t] = eb + sp;
        if (b == 0) cnt[t] = tot[t];
    }
    const int tok = b * 256 + t;
    const int e = eidx[tok];
    int wrank = 0;
#pragma unroll
    for (int q = 0; q < 8; q++) {
        unsigned long long m = __ballot(e == q);
        if (e == q) wrank = __popcll(m & ((1ull << lane) - 1ull));
        if (lane == 0) wcnt[wid][q] = __popcll(m);
    }
    __syncthreads();
    int wbase = 0;
#pragma unroll
    for (int w = 0; w < 4; w++)
        if (w < wid) wbase += wcnt[w][e];
    list[bb8[e] + wbase + wrank] = tok;
}

// ---------------------------------------------------------------------------
// GEMM1 + hidden conv(wo): blocks [0,1632) = proven 128x256 BK=64
// single-buffer 2-barrier grouped-GEMM; blocks [1632,6240) convert
// wo -> wob bf16 transposed, hiding 151MB under gemm1's compute.
// ---------------------------------------------------------------------------
__global__ __launch_bounds__(256, 2) void k_gemm1(
    const unsigned short* __restrict__ A, const unsigned short* __restrict__ Bw,
    const int* __restrict__ list, const int* __restrict__ cnt,
    unsigned short* __restrict__ Hout,
    const float* __restrict__ wo, unsigned short* __restrict__ wob)
{
    constexpr int K   = DIM;
    constexpr int N   = FFD;
    constexpr int TNT = N / 256;                  // 12
    constexpr int NWG = 1632;
    __shared__ unsigned short Asm[128 * 64];      // 16 KB
    __shared__ unsigned short Bsm[256 * 64];      // 32 KB
    __shared__ int tokrow[128];
    __shared__ int spref[9];
    __shared__ int ebase[8];

    const int t = threadIdx.x, lane = t & 63, wid = t >> 6;

    if (blockIdx.x >= NWG) {
        float (*tile)[65] = reinterpret_cast<float(*)[65]>(Bsm);
        const int bb = blockIdx.x - NWG;
        const int bc = DIM >> 6, br = FFD >> 6;
        const int e = bb / (bc * br);
        const int rem = bb - e * bc * br;
        const int rt = rem / bc, ct = rem - rt * bc;
        {
            const int r = t >> 2, c4 = (t & 3) << 4;
            const float* src = wo + ((size_t)e * FFD + rt * 64 + r) * DIM + ct * 64 + c4;
#pragma unroll
            for (int q = 0; q < 4; q++) {
                float4 f = ((const float4*)src)[q];
                tile[r][c4 + q * 4 + 0] = f.x;
                tile[r][c4 + q * 4 + 1] = f.y;
                tile[r][c4 + q * 4 + 2] = f.z;
                tile[r][c4 + q * 4 + 3] = f.w;
            }
        }
        __syncthreads();
        {
            const int c = t >> 2, r4 = (t & 3) << 4;
            u16x8 o0, o1;
#pragma unroll
            for (int j = 0; j < 8; j++)  o0[j] = f2bf(tile[r4 + j][c]);
#pragma unroll
            for (int j = 0; j < 8; j++)  o1[j] = f2bf(tile[r4 + 8 + j][c]);
            unsigned short* dst = wob + ((size_t)e * DIM + ct * 64 + c) * FFD + rt * 64 + r4;
            *(u16x8*)dst       = o0;
            *(u16x8*)(dst + 8) = o1;
        }
        return;
    }

    if (t == 0) {
        int p = 0, qq = 0;
        spref[0] = 0;
#pragma unroll
        for (int e = 0; e < 8; e++) {
            ebase[e] = qq; qq += cnt[e];
            p += (cnt[e] + 127) >> 7;
            spref[e + 1] = p;
        }
    }
    __syncthreads();
    const int total = spref[8] * TNT;
    const int moff = (wid >> 1) * 64, noff = (wid & 1) * 128;
    const int lr = lane & 15, lq = lane >> 4;

    const int xcd = blockIdx.x & 7, rr8 = blockIdx.x >> 3;
    const int bid = xcd * (NWG >> 3) + rr8;

    int arow[4], asub[4], brow[8], bsub[8];
#pragma unroll
    for (int i = 0; i < 4; i++) {
        int c = (wid * 4 + i) * 64 + lane;
        arow[i] = c >> 3;
        asub[i] = (c & 7) ^ (arow[i] & 7);
    }
#pragma unroll
    for (int i = 0; i < 8; i++) {
        int c = (wid * 8 + i) * 64 + lane;
        brow[i] = c >> 3;
        bsub[i] = (c & 7) ^ (brow[i] & 7);
    }

    for (int w = bid; w < total; w += NWG) {
        const int gm = w / TNT, tn = w - gm * TNT;
        int e = 0;
        while (gm >= spref[e + 1]) e++;
        const int ce = cnt[e], eb = ebase[e];
        const int m0 = (gm - spref[e]) * 128, n0 = tn * 256;

        __syncthreads();
        if (t < 128)
            tokrow[t] = (m0 + t < ce) ? list[eb + m0 + t] : list[eb];
        __syncthreads();

        const unsigned short* aP[4];
        const unsigned short* bP[8];
#pragma unroll
        for (int i = 0; i < 4; i++)
            aP[i] = A + (size_t)tokrow[arow[i]] * K + asub[i] * 8;
#pragma unroll
        for (int i = 0; i < 8; i++)
            bP[i] = Bw + ((size_t)e * N + n0 + brow[i]) * K + bsub[i] * 8;

        f32x4 acc[4][8];
#pragma unroll
        for (int mi = 0; mi < 4; mi++)
#pragma unroll
            for (int ni = 0; ni < 8; ni++) acc[mi][ni] = (f32x4){0, 0, 0, 0};

        for (int k0 = 0; k0 < K; k0 += 64) {
#pragma unroll
            for (int i = 0; i < 4; i++)
                gload16(aP[i] + k0, Asm + (wid * 4 + i) * 512);
#pragma unroll
            for (int i = 0; i < 8; i++)
                gload16(bP[i] + k0, Bsm + (wid * 8 + i) * 512);
            __syncthreads();
#pragma unroll
            for (int kf = 0; kf < 2; kf++) {
                const int phys = ((kf * 4 + lq) ^ (lr & 7)) * 8;
                bf16x8 af[4], bfr[8];
#pragma unroll
                for (int mi = 0; mi < 4; mi++)
                    af[mi] = as_bf(*(const u16x8*)&Asm[(moff + mi * 16 + lr) * 64 + phys]);
#pragma unroll
                for (int ni = 0; ni < 8; ni++)
                    bfr[ni] = as_bf(*(const u16x8*)&Bsm[(noff + ni * 16 + lr) * 64 + phys]);
#pragma unroll
                for (int mi = 0; mi < 4; mi++)
#pragma unroll
                    for (int ni = 0; ni < 8; ni++)
                        acc[mi][ni] = __builtin_amdgcn_mfma_f32_16x16x32_bf16(
                            af[mi], bfr[ni], acc[mi][ni], 0, 0, 0);
            }
            __syncthreads();
        }

#pragma unroll
        for (int mi = 0; mi < 4; mi++) {
#pragma unroll
            for (int r4 = 0; r4 < 4; r4++) {
                const int row = moff + mi * 16 + lq * 4 + r4;
                if (m0 + row < ce) {
                    unsigned short* hp = Hout + (size_t)(eb + m0 + row) * FFD + n0 + noff;
#pragma unroll
                    for (int ni = 0; ni < 8; ni++) {
                        float v = acc[mi][ni][r4];
                        v = v > 0.f ? v : 0.f;
                        hp[ni * 16 + lr] = f2bf(v);
                    }
                }
            }
        }
    }
}

// ---------------------------------------------------------------------------
// GEMM2 (proven ~116us): 128x256 tile, BK=64, single-buffer 2-barrier,
// dense A rows from permuted H.
// ---------------------------------------------------------------------------
__global__ __launch_bounds__(256, 2) void k_gemm2(
    const unsigned short* __restrict__ A, const unsigned short* __restrict__ Bw,
    const int* __restrict__ list, const int* __restrict__ cnt,
    const float* __restrict__ hs, const float* __restrict__ topp,
    float* __restrict__ out)
{
    constexpr int K   = FFD;
    constexpr int N   = DIM;
    constexpr int TNT = N / 256;                  // 3
    __shared__ unsigned short Asm[128 * 64];
    __shared__ unsigned short Bsm[256 * 64];
    __shared__ int tokrow[128];
    __shared__ int spref[9];
    __shared__ int ebase[8];

    const int t = threadIdx.x, lane = t & 63, wid = t >> 6;
    if (t == 0) {
        int p = 0, qq = 0;
        spref[0] = 0;
#pragma unroll
        for (int e = 0; e < 8; e++) {
            ebase[e] = qq; qq += cnt[e];
            p += (cnt[e] + 127) >> 7;
            spref[e + 1] = p;
        }
    }
    __syncthreads();
    const int total = spref[8] * TNT;
    const int moff = (wid >> 1) * 64, noff = (wid & 1) * 128;
    const int lr = lane & 15, lq = lane >> 4;

    const int nwg = gridDim.x;
    const int xcd = blockIdx.x & 7, rr8 = blockIdx.x >> 3;
    const int qd = nwg >> 3, rm = nwg & 7;
    const int bid = (xcd < rm ? xcd * (qd + 1) : rm * (qd + 1) + (xcd - rm) * qd) + rr8;

    int arow[4], asub[4], brow[8], bsub[8];
#pragma unroll
    for (int i = 0; i < 4; i++) {
        int c = (wid * 4 + i) * 64 + lane;
        arow[i] = c >> 3;
        asub[i] = (c & 7) ^ (arow[i] & 7);
    }
#pragma unroll
    for (int i = 0; i < 8; i++) {
        int c = (wid * 8 + i) * 64 + lane;
        brow[i] = c >> 3;
        bsub[i] = (c & 7) ^ (brow[i] & 7);
    }

    for (int w = bid; w < total; w += gridDim.x) {
        const int gm = w / TNT, tn = w - gm * TNT;
        int e = 0;
        while (gm >= spref[e + 1]) e++;
        const int ce = cnt[e], eb = ebase[e];
        const int m0 = (gm - spref[e]) * 128, n0 = tn * 256;

        __syncthreads();
        if (t < 128)
            tokrow[t] = (m0 + t < ce) ? list[eb + m0 + t] : list[eb];
        __syncthreads();

        const unsigned short* aP[4];
        const unsigned short* bP[8];
#pragma unroll
        for (int i = 0; i < 4; i++) {
            const int drow = (m0 + arow[i] < ce) ? (m0 + arow[i]) : (ce - 1);
            aP[i] = A + (size_t)(eb + drow) * K + asub[i] * 8;
        }
#pragma unroll
        for (int i = 0; i < 8; i++)
            bP[i] = Bw + ((size_t)e * N + n0 + brow[i]) * K + bsub[i] * 8;

        f32x4 acc[4][8];
#pragma unroll
        for (int mi = 0; mi < 4; mi++)
#pragma unroll
            for (int ni = 0; ni < 8; ni++) acc[mi][ni] = (f32x4){0, 0, 0, 0};

        for (int k0 = 0; k0 < K; k0 += 64) {
#pragma unroll
            for (int i = 0; i < 4; i++)
                gload16(aP[i] + k0, Asm + (wid * 4 + i) * 512);
#pragma unroll
            for (int i = 0; i < 8; i++)
                gload16(bP[i] + k0, Bsm + (wid * 8 + i) * 512);
            __syncthreads();
#pragma unroll
            for (int kf = 0; kf < 2; kf++) {
                const int phys = ((kf * 4 + lq) ^ (lr & 7)) * 8;
                bf16x8 af[4], bfr[8];
#pragma unroll
                for (int mi = 0; mi < 4; mi++)
                    af[mi] = as_bf(*(const u16x8*)&Asm[(moff + mi * 16 + lr) * 64 + phys]);
#pragma unroll
                for (int ni = 0; ni < 8; ni++)
                    bfr[ni] = as_bf(*(const u16x8*)&Bsm[(noff + ni * 16 + lr) * 64 + phys]);
#pragma unroll
                for (int mi = 0; mi < 4; mi++)
#pragma unroll
                    for (int ni = 0; ni < 8; ni++)
                        acc[mi][ni] = __builtin_amdgcn_mfma_f32_16x16x32_bf16(
                            af[mi], bfr[ni], acc[mi][ni], 0, 0, 0);
            }
            __syncthreads();
        }

#pragma unroll
        for (int mi = 0; mi < 4; mi++) {
#pragma unroll
            for (int r4 = 0; r4 < 4; r4++) {
                const int row = moff + mi * 16 + lq * 4 + r4;
                if (m0 + row < ce) {
                    const int tok = tokrow[row];
                    const float tp = topp[tok];
#pragma unroll
                    for (int ni = 0; ni < 8; ni++) {
                        const size_t idx = (size_t)tok * DIM + n0 + noff + ni * 16 + lr;
                        out[idx] = hs[idx] + tp * acc[mi][ni][r4];
                    }
                }
            }
        }
    }
}

// ---------------------------------------------------------------------------
extern "C" void kernel_launch(void* const* d_in, const int* in_sizes, int n_in,
                              void* d_out, int out_size, void* d_ws, size_t ws_size,
                              hipStream_t stream)
{
    const float* hs  = (const float*)d_in[0];
    const float* lnw = (const float*)d_in[1];
    const float* rw  = (const float*)d_in[2];
    const float* wi  = (const float*)d_in[3];
    const float* wo  = (const float*)d_in[4];

    float* out        = (float*)d_out;
    float* out_logits = out + (size_t)N_TOK * DIM;
    float* out_eidx   = out_logits + (size_t)N_TOK * NEXP;

    char* ws = (char*)d_ws;
    size_t off = 0;
    int*   cnt     = (int*)(ws + off);         off += 256;
    int*   list    = (int*)(ws + off);         off += (size_t)N_TOK * 4;
    float* topp    = (float*)(ws + off);       off += (size_t)N_TOK * 4;
    int*   eidx    = (int*)(ws + off);         off += (size_t)N_TOK * 4;
    int*   blkhist = (int*)(ws + off);         off += 4096;
    unsigned short* xn  = (unsigned short*)(ws + off); off += (size_t)N_TOK * DIM * 2;
    unsigned short* Hb  = (unsigned short*)(ws + off); off += (size_t)N_TOK * FFD * 2;
    unsigned short* wob = (unsigned short*)(ws + off);

    // wi^T (bf16 [e][F][D]) lives in d_out's first 37.75 MB: dead before
    // GEMM2's epilogue writes `out` (GEMMs run sequentially).
    unsigned short* wib = (unsigned short*)d_out;

    k_setup<<<8704, 256, 0, stream>>>(wi, wib, hs, lnw, rw,
                                      out_logits, out_eidx, topp, eidx, xn);
    k_hist<<<64, 256, 0, stream>>>(eidx, blkhist);
    k_scatter<<<64, 256, 0, stream>>>(eidx, blkhist, list, cnt);
    k_gemm1<<<6240, 256, 0, stream>>>(xn, wib, list, cnt, Hb, wo, wob);
    k_gemm2<<<408, 256, 0, stream>>>(Hb, wob, list, cnt, hs, topp, out);
}